// Round 4
// baseline (877.072 us; speedup 1.0000x reference)
//
#include <hip/hip_runtime.h>

#define NN 131072
#define NE 1048576
#define DD 64
#define NG 32
#define NPG 4096
#define SCAN_B 512  // 512 blocks x 256 = 131072

__device__ __forceinline__ float bf2f(unsigned short u) {
  return __uint_as_float(((unsigned int)u) << 16);
}
__device__ __forceinline__ unsigned short f2bf(float f) {
  unsigned int u = __float_as_uint(f);
  return (unsigned short)((u + 0x7FFFu + ((u >> 16) & 1u)) >> 16);
}
__device__ __forceinline__ unsigned int pack2(float a, float b) {
  return (unsigned int)f2bf(a) | ((unsigned int)f2bf(b) << 16);
}

// ---------------- degree histogram ----------------
extern "C" __global__ void k_count(const int* __restrict__ col, int* __restrict__ cnt) {
  int e = blockIdx.x * 256 + threadIdx.x;
  if (e < NE) atomicAdd(&cnt[col[e]], 1);
}

// ---------------- exclusive scan of cnt -> starts (3 phases) ----------------
extern "C" __global__ __launch_bounds__(256) void k_scan1(const int* __restrict__ cnt,
                                                          int* __restrict__ partial) {
  __shared__ int s[256];
  int t = threadIdx.x;
  s[t] = cnt[blockIdx.x * 256 + t];
  __syncthreads();
  for (int off = 128; off > 0; off >>= 1) {
    if (t < off) s[t] += s[t + off];
    __syncthreads();
  }
  if (t == 0) partial[blockIdx.x] = s[0];
}

extern "C" __global__ __launch_bounds__(512) void k_scan2(const int* __restrict__ partial,
                                                          int* __restrict__ pexcl) {
  __shared__ int s[512];
  int t = threadIdx.x;
  int v = partial[t];
  s[t] = v;
  __syncthreads();
  for (int off = 1; off < 512; off <<= 1) {
    int u = (t >= off) ? s[t - off] : 0;
    __syncthreads();
    s[t] += u;
    __syncthreads();
  }
  pexcl[t] = s[t] - v;  // exclusive
}

// also emits dis = rsqrt(deg+1) (folded former k_dis)
extern "C" __global__ __launch_bounds__(256) void k_scan3(const int* __restrict__ cnt,
                                                          const int* __restrict__ pexcl,
                                                          int* __restrict__ starts,
                                                          int* __restrict__ cursor,
                                                          float* __restrict__ dis) {
  __shared__ int s[256];
  int t = threadIdx.x;
  int i = blockIdx.x * 256 + t;
  int v = cnt[i];
  s[t] = v;
  __syncthreads();
  for (int off = 1; off < 256; off <<= 1) {
    int u = (t >= off) ? s[t - off] : 0;
    __syncthreads();
    s[t] += u;
    __syncthreads();
  }
  int excl = s[t] - v + pexcl[blockIdx.x];
  starts[i] = excl;
  cursor[i] = excl;
  dis[i] = rsqrtf((float)v + 1.0f);
}

// ---------------- CSR fill: bucket edges by destination, packed (nbr, wn) ----------------
extern "C" __global__ void k_fill(const int* __restrict__ row, const int* __restrict__ col,
                                  const float* __restrict__ dis, int* __restrict__ cursor,
                                  int2* __restrict__ edges) {
  int e = blockIdx.x * 256 + threadIdx.x;
  if (e < NE) {
    int r = row[e], c = col[e];
    int pos = atomicAdd(&cursor[c], 1);
    edges[pos] = make_int2(r, __float_as_int(dis[r] * dis[c]));
  }
}

// ---------------- GEMM1: h1 = x @ W1  (bf16 output, register-pressure bounded) ----------------
extern "C" __global__ __launch_bounds__(256, 4) void k_gemm1(
    const float* __restrict__ x, const float* __restrict__ W1, unsigned short* __restrict__ h1b) {
  __shared__ float4 wl[DD * 16];  // W1 as [k][j4], 16 KB
  int t = threadIdx.x;
  for (int i = t; i < DD * 16; i += 256) wl[i] = reinterpret_cast<const float4*>(W1)[i];
  __syncthreads();
  int row = blockIdx.x * 256 + t;
  const float4* xp = reinterpret_cast<const float4*>(x + (size_t)row * DD);
  float4 xr[16];  // full x row in registers (64 VGPR), read once, exact fp32
#pragma unroll
  for (int kk = 0; kk < 16; ++kk) xr[kk] = xp[kk];
  uint4* hp = reinterpret_cast<uint4*>(h1b + (size_t)row * DD);
  // 4 chunks of 16 output columns each; acc = 16 VGPR per chunk
  for (int jc = 0; jc < 4; ++jc) {  // NOT unrolled: bounds live range
    float4 acc[4];
#pragma unroll
    for (int j = 0; j < 4; ++j) acc[j] = make_float4(0.f, 0.f, 0.f, 0.f);
#pragma unroll
    for (int kk = 0; kk < 16; ++kk) {
      float4 a = xr[kk];
#pragma unroll
      for (int j = 0; j < 4; ++j) {
        float4 w0 = wl[(4 * kk + 0) * 16 + jc * 4 + j];
        float4 w1 = wl[(4 * kk + 1) * 16 + jc * 4 + j];
        float4 w2 = wl[(4 * kk + 2) * 16 + jc * 4 + j];
        float4 w3 = wl[(4 * kk + 3) * 16 + jc * 4 + j];
        acc[j].x += a.x * w0.x + a.y * w1.x + a.z * w2.x + a.w * w3.x;
        acc[j].y += a.x * w0.y + a.y * w1.y + a.z * w2.y + a.w * w3.y;
        acc[j].z += a.x * w0.z + a.y * w1.z + a.z * w2.z + a.w * w3.z;
        acc[j].w += a.x * w0.w + a.y * w1.w + a.z * w2.w + a.w * w3.w;
      }
    }
    hp[jc * 2 + 0] = make_uint4(pack2(acc[0].x, acc[0].y), pack2(acc[0].z, acc[0].w),
                                pack2(acc[1].x, acc[1].y), pack2(acc[1].z, acc[1].w));
    hp[jc * 2 + 1] = make_uint4(pack2(acc[2].x, acc[2].y), pack2(acc[2].z, acc[2].w),
                                pack2(acc[3].x, acc[3].y), pack2(acc[3].z, acc[3].w));
  }
}

// ---- fused: agg1 gather (wave per node, bf16) + bias + relu + @W2 -> h2 [N,3] f32 ----
extern "C" __global__ __launch_bounds__(256) void k_agg1f(
    const unsigned short* __restrict__ h1b, const int* __restrict__ starts,
    const int* __restrict__ cnt, const int2* __restrict__ edges,
    const float* __restrict__ b1, const float* __restrict__ W2, float* __restrict__ h2) {
  int lane = threadIdx.x & 63;
  int node = blockIdx.x * 4 + (threadIdx.x >> 6);
  int start = starts[node];
  int deg = cnt[node];
  float a = bf2f(h1b[(size_t)node * DD + lane]) / (float)(deg + 1);  // self: dis^2 = 1/(deg+1)
  // preload up to 64 edges into lanes, broadcast via shfl
  int nb = 0;
  float w = 0.f;
  if (lane < deg) {
    int2 ed = edges[start + lane];
    nb = ed.x;
    w = __int_as_float(ed.y);
  }
  int m = deg < 64 ? deg : 64;
  int e = 0;
  for (; e + 4 <= m; e += 4) {  // 4 independent loads in flight
    int r0 = __shfl(nb, e + 0), r1 = __shfl(nb, e + 1);
    int r2 = __shfl(nb, e + 2), r3 = __shfl(nb, e + 3);
    float w0 = __shfl(w, e + 0), w1 = __shfl(w, e + 1);
    float w2 = __shfl(w, e + 2), w3 = __shfl(w, e + 3);
    float v0 = bf2f(h1b[(size_t)r0 * DD + lane]);
    float v1 = bf2f(h1b[(size_t)r1 * DD + lane]);
    float v2 = bf2f(h1b[(size_t)r2 * DD + lane]);
    float v3 = bf2f(h1b[(size_t)r3 * DD + lane]);
    a += w0 * v0 + w1 * v1 + w2 * v2 + w3 * v3;
  }
  for (; e < m; ++e) {
    int r = __shfl(nb, e);
    float we = __shfl(w, e);
    a += we * bf2f(h1b[(size_t)r * DD + lane]);
  }
  for (int e2 = start + 64; e2 < start + deg; ++e2) {  // rare tail (deg > 64)
    int2 ed = edges[e2];
    a += __int_as_float(ed.y) * bf2f(h1b[(size_t)ed.x * DD + lane]);
  }
  // layer2 node work: z = relu(a + b1); h2 = z @ W2
  float z = fmaxf(a + b1[lane], 0.f);
  float v0 = z * W2[lane * 3 + 0];
  float v1 = z * W2[lane * 3 + 1];
  float v2 = z * W2[lane * 3 + 2];
#pragma unroll
  for (int off = 32; off > 0; off >>= 1) {
    v0 += __shfl_xor(v0, off);
    v1 += __shfl_xor(v1, off);
    v2 += __shfl_xor(v2, off);
  }
  if (lane == 0) {
    h2[node * 3 + 0] = v0;
    h2[node * 3 + 1] = v1;
    h2[node * 3 + 2] = v2;
  }
}

// ---------------- seed out with b2 ----------------
extern "C" __global__ void k_initout(const float* __restrict__ b2, float* __restrict__ out) {
  int i = threadIdx.x;
  if (i < NG * 3) out[i] = b2[i % 3];
}

// ---- fused layer-2 aggregation + mean pool: thread/node gather h2, block-reduce, atomic ----
extern "C" __global__ __launch_bounds__(256) void k_agg2pool(
    const float* __restrict__ h2, const int* __restrict__ starts, const int* __restrict__ cnt,
    const int2* __restrict__ edges, float* __restrict__ out) {
  int n = blockIdx.x * 256 + threadIdx.x;
  int start = starts[n], deg = cnt[n];
  float selfw = 1.0f / (float)(deg + 1);
  float s0 = h2[n * 3 + 0] * selfw;
  float s1 = h2[n * 3 + 1] * selfw;
  float s2 = h2[n * 3 + 2] * selfw;
  for (int e = start; e < start + deg; ++e) {
    int2 ed = edges[e];
    float we = __int_as_float(ed.y);
    s0 += we * h2[ed.x * 3 + 0];
    s1 += we * h2[ed.x * 3 + 1];
    s2 += we * h2[ed.x * 3 + 2];
  }
  __shared__ float red[3][256];
  int t = threadIdx.x;
  red[0][t] = s0; red[1][t] = s1; red[2][t] = s2;
  __syncthreads();
  for (int off = 128; off > 0; off >>= 1) {
    if (t < off) {
      red[0][t] += red[0][t + off];
      red[1][t] += red[1][t + off];
      red[2][t] += red[2][t + off];
    }
    __syncthreads();
  }
  if (t == 0) {
    int g = blockIdx.x >> 4;  // 16 blocks of 256 nodes per 4096-node graph
    const float inv = 1.0f / (float)NPG;
    atomicAdd(&out[g * 3 + 0], red[0][0] * inv);
    atomicAdd(&out[g * 3 + 1], red[1][0] * inv);
    atomicAdd(&out[g * 3 + 2], red[2][0] * inv);
  }
}

extern "C" void kernel_launch(void* const* d_in, const int* in_sizes, int n_in,
                              void* d_out, int out_size, void* d_ws, size_t ws_size,
                              hipStream_t stream) {
  const float* x  = (const float*)d_in[0];
  const int*   ei = (const int*)d_in[1];
  const float* W1 = (const float*)d_in[3];
  const float* b1 = (const float*)d_in[4];
  const float* W2 = (const float*)d_in[5];
  const float* b2 = (const float*)d_in[6];
  const int* row = ei;
  const int* col = ei + NE;
  float* out = (float*)d_out;

  // workspace layout (byte offsets)
  char* ws = (char*)d_ws;
  int*   cnt     = (int*)(ws + 0);                 // 512 KB
  float* dis     = (float*)(ws + (1u << 19));      // 512 KB
  int*   starts  = (int*)(ws + (2u << 19));        // 512 KB
  int*   cursor  = (int*)(ws + (3u << 19));        // 512 KB
  int*   partial = (int*)(ws + (4u << 19));        // 2 KB
  int*   pexcl   = (int*)(ws + (4u << 19) + 4096); // 2 KB
  int2*  edges   = (int2*)(ws + (5u << 19));       // 8 MB
  unsigned short* h1b = (unsigned short*)(ws + (5u << 19) + (1u << 23));  // 16 MB
  float* h2      = (float*)(ws + (5u << 19) + (1u << 23) + (1u << 24));   // 1.5 MB

  hipMemsetAsync(cnt, 0, NN * sizeof(int), stream);
  k_count<<<NE / 256, 256, 0, stream>>>(col, cnt);
  k_scan1<<<SCAN_B, 256, 0, stream>>>(cnt, partial);
  k_scan2<<<1, 512, 0, stream>>>(partial, pexcl);
  k_scan3<<<SCAN_B, 256, 0, stream>>>(cnt, pexcl, starts, cursor, dis);
  k_fill<<<NE / 256, 256, 0, stream>>>(row, col, dis, cursor, edges);
  k_gemm1<<<NN / 256, 256, 0, stream>>>(x, W1, h1b);
  k_agg1f<<<NN / 4, 256, 0, stream>>>(h1b, starts, cnt, edges, b1, W2, h2);
  k_initout<<<1, 96, 0, stream>>>(b2, out);
  k_agg2pool<<<NN / 256, 256, 0, stream>>>(h2, starts, cnt, edges, out);
}

// Round 5
// 241.378 us; speedup vs baseline: 3.6336x; 3.6336x over previous
//
#include <hip/hip_runtime.h>

#define NN 131072
#define NE 1048576
#define DD 64
#define NG 32
#define NPG 4096
#define SCAN_B 512  // 512 blocks x 256 = 131072

__device__ __forceinline__ float bf2f(unsigned short u) {
  return __uint_as_float(((unsigned int)u) << 16);
}
__device__ __forceinline__ unsigned short f2bf(float f) {
  unsigned int u = __float_as_uint(f);
  return (unsigned short)((u + 0x7FFFu + ((u >> 16) & 1u)) >> 16);
}
__device__ __forceinline__ unsigned int pack2(float a, float b) {
  return (unsigned int)f2bf(a) | ((unsigned int)f2bf(b) << 16);
}

// ---------------- degree histogram ----------------
extern "C" __global__ void k_count(const int* __restrict__ col, int* __restrict__ cnt) {
  int e = blockIdx.x * 256 + threadIdx.x;
  if (e < NE) atomicAdd(&cnt[col[e]], 1);
}

// ---------------- exclusive scan of cnt -> starts (3 phases) ----------------
extern "C" __global__ __launch_bounds__(256) void k_scan1(const int* __restrict__ cnt,
                                                          int* __restrict__ partial) {
  __shared__ int s[256];
  int t = threadIdx.x;
  s[t] = cnt[blockIdx.x * 256 + t];
  __syncthreads();
  for (int off = 128; off > 0; off >>= 1) {
    if (t < off) s[t] += s[t + off];
    __syncthreads();
  }
  if (t == 0) partial[blockIdx.x] = s[0];
}

extern "C" __global__ __launch_bounds__(512) void k_scan2(const int* __restrict__ partial,
                                                          int* __restrict__ pexcl) {
  __shared__ int s[512];
  int t = threadIdx.x;
  int v = partial[t];
  s[t] = v;
  __syncthreads();
  for (int off = 1; off < 512; off <<= 1) {
    int u = (t >= off) ? s[t - off] : 0;
    __syncthreads();
    s[t] += u;
    __syncthreads();
  }
  pexcl[t] = s[t] - v;  // exclusive
}

// also emits dis = rsqrt(deg+1) (folded former k_dis)
extern "C" __global__ __launch_bounds__(256) void k_scan3(const int* __restrict__ cnt,
                                                          const int* __restrict__ pexcl,
                                                          int* __restrict__ starts,
                                                          int* __restrict__ cursor,
                                                          float* __restrict__ dis) {
  __shared__ int s[256];
  int t = threadIdx.x;
  int i = blockIdx.x * 256 + t;
  int v = cnt[i];
  s[t] = v;
  __syncthreads();
  for (int off = 1; off < 256; off <<= 1) {
    int u = (t >= off) ? s[t - off] : 0;
    __syncthreads();
    s[t] += u;
    __syncthreads();
  }
  int excl = s[t] - v + pexcl[blockIdx.x];
  starts[i] = excl;
  cursor[i] = excl;
  dis[i] = rsqrtf((float)v + 1.0f);
}

// ---------------- CSR fill: bucket edges by destination, packed (nbr, wn) ----------------
extern "C" __global__ void k_fill(const int* __restrict__ row, const int* __restrict__ col,
                                  const float* __restrict__ dis, int* __restrict__ cursor,
                                  int2* __restrict__ edges) {
  int e = blockIdx.x * 256 + threadIdx.x;
  if (e < NE) {
    int r = row[e], c = col[e];
    int pos = atomicAdd(&cursor[c], 1);
    edges[pos] = make_int2(r, __float_as_int(dis[r] * dis[c]));
  }
}

// ---------------- GEMM1: h1 = x @ W1 (bf16 out). 4 threads/row, 16 cols/thread. ----------------
// Live set per thread: acc[4] (16 VGPR) + streamed a + 4 W-quads -> no spill, no cap needed.
extern "C" __global__ __launch_bounds__(256) void k_gemm1(
    const float* __restrict__ x, const float* __restrict__ W1, unsigned short* __restrict__ h1b) {
  __shared__ float4 wl[DD * 16];  // W1 as [k][j4], 16 KB
  int t = threadIdx.x;
  for (int i = t; i < DD * 16; i += 256) wl[i] = reinterpret_cast<const float4*>(W1)[i];
  __syncthreads();
  int row = blockIdx.x * 64 + (t >> 2);
  int jc = t & 3;  // column chunk: cols [16*jc, 16*jc+16)
  const float4* xp = reinterpret_cast<const float4*>(x + (size_t)row * DD);
  float4 acc[4];
#pragma unroll
  for (int j = 0; j < 4; ++j) acc[j] = make_float4(0.f, 0.f, 0.f, 0.f);
#pragma unroll
  for (int kk = 0; kk < 16; ++kk) {
    float4 a = xp[kk];  // streamed; 4 threads/row broadcast same line
#pragma unroll
    for (int j = 0; j < 4; ++j) {
      float4 w0 = wl[(4 * kk + 0) * 16 + jc * 4 + j];
      float4 w1 = wl[(4 * kk + 1) * 16 + jc * 4 + j];
      float4 w2 = wl[(4 * kk + 2) * 16 + jc * 4 + j];
      float4 w3 = wl[(4 * kk + 3) * 16 + jc * 4 + j];
      acc[j].x += a.x * w0.x + a.y * w1.x + a.z * w2.x + a.w * w3.x;
      acc[j].y += a.x * w0.y + a.y * w1.y + a.z * w2.y + a.w * w3.y;
      acc[j].z += a.x * w0.z + a.y * w1.z + a.z * w2.z + a.w * w3.z;
      acc[j].w += a.x * w0.w + a.y * w1.w + a.z * w2.w + a.w * w3.w;
    }
  }
  uint4* hp = reinterpret_cast<uint4*>(h1b + (size_t)row * DD + jc * 16);
  hp[0] = make_uint4(pack2(acc[0].x, acc[0].y), pack2(acc[0].z, acc[0].w),
                     pack2(acc[1].x, acc[1].y), pack2(acc[1].z, acc[1].w));
  hp[1] = make_uint4(pack2(acc[2].x, acc[2].y), pack2(acc[2].z, acc[2].w),
                     pack2(acc[3].x, acc[3].y), pack2(acc[3].z, acc[3].w));
}

// ---- fused: agg1 gather (wave per node, bf16) + bias + relu + @W2 -> h2 [N,3] f32 ----
extern "C" __global__ __launch_bounds__(256) void k_agg1f(
    const unsigned short* __restrict__ h1b, const int* __restrict__ starts,
    const int* __restrict__ cnt, const int2* __restrict__ edges,
    const float* __restrict__ b1, const float* __restrict__ W2, float* __restrict__ h2) {
  int lane = threadIdx.x & 63;
  int node = blockIdx.x * 4 + (threadIdx.x >> 6);
  int start = starts[node];
  int deg = cnt[node];
  float a = bf2f(h1b[(size_t)node * DD + lane]) / (float)(deg + 1);  // self: dis^2 = 1/(deg+1)
  // preload up to 64 edges into lanes, broadcast via shfl
  int nb = 0;
  float w = 0.f;
  if (lane < deg) {
    int2 ed = edges[start + lane];
    nb = ed.x;
    w = __int_as_float(ed.y);
  }
  int m = deg < 64 ? deg : 64;
  int e = 0;
  for (; e + 4 <= m; e += 4) {  // 4 independent loads in flight
    int r0 = __shfl(nb, e + 0), r1 = __shfl(nb, e + 1);
    int r2 = __shfl(nb, e + 2), r3 = __shfl(nb, e + 3);
    float w0 = __shfl(w, e + 0), w1 = __shfl(w, e + 1);
    float w2 = __shfl(w, e + 2), w3 = __shfl(w, e + 3);
    float v0 = bf2f(h1b[(size_t)r0 * DD + lane]);
    float v1 = bf2f(h1b[(size_t)r1 * DD + lane]);
    float v2 = bf2f(h1b[(size_t)r2 * DD + lane]);
    float v3 = bf2f(h1b[(size_t)r3 * DD + lane]);
    a += w0 * v0 + w1 * v1 + w2 * v2 + w3 * v3;
  }
  for (; e < m; ++e) {
    int r = __shfl(nb, e);
    float we = __shfl(w, e);
    a += we * bf2f(h1b[(size_t)r * DD + lane]);
  }
  for (int e2 = start + 64; e2 < start + deg; ++e2) {  // rare tail (deg > 64)
    int2 ed = edges[e2];
    a += __int_as_float(ed.y) * bf2f(h1b[(size_t)ed.x * DD + lane]);
  }
  // layer2 node work: z = relu(a + b1); h2 = z @ W2
  float z = fmaxf(a + b1[lane], 0.f);
  float v0 = z * W2[lane * 3 + 0];
  float v1 = z * W2[lane * 3 + 1];
  float v2 = z * W2[lane * 3 + 2];
#pragma unroll
  for (int off = 32; off > 0; off >>= 1) {
    v0 += __shfl_xor(v0, off);
    v1 += __shfl_xor(v1, off);
    v2 += __shfl_xor(v2, off);
  }
  if (lane == 0) {
    h2[node * 3 + 0] = v0;
    h2[node * 3 + 1] = v1;
    h2[node * 3 + 2] = v2;
  }
}

// ---------------- seed out with b2 ----------------
extern "C" __global__ void k_initout(const float* __restrict__ b2, float* __restrict__ out) {
  int i = threadIdx.x;
  if (i < NG * 3) out[i] = b2[i % 3];
}

// ---- fused layer-2 aggregation + mean pool: thread/node gather h2, block-reduce, atomic ----
extern "C" __global__ __launch_bounds__(256) void k_agg2pool(
    const float* __restrict__ h2, const int* __restrict__ starts, const int* __restrict__ cnt,
    const int2* __restrict__ edges, float* __restrict__ out) {
  int n = blockIdx.x * 256 + threadIdx.x;
  int start = starts[n], deg = cnt[n];
  float selfw = 1.0f / (float)(deg + 1);
  float s0 = h2[n * 3 + 0] * selfw;
  float s1 = h2[n * 3 + 1] * selfw;
  float s2 = h2[n * 3 + 2] * selfw;
  for (int e = start; e < start + deg; ++e) {
    int2 ed = edges[e];
    float we = __int_as_float(ed.y);
    s0 += we * h2[ed.x * 3 + 0];
    s1 += we * h2[ed.x * 3 + 1];
    s2 += we * h2[ed.x * 3 + 2];
  }
  __shared__ float red[3][256];
  int t = threadIdx.x;
  red[0][t] = s0; red[1][t] = s1; red[2][t] = s2;
  __syncthreads();
  for (int off = 128; off > 0; off >>= 1) {
    if (t < off) {
      red[0][t] += red[0][t + off];
      red[1][t] += red[1][t + off];
      red[2][t] += red[2][t + off];
    }
    __syncthreads();
  }
  if (t == 0) {
    int g = blockIdx.x >> 4;  // 16 blocks of 256 nodes per 4096-node graph
    const float inv = 1.0f / (float)NPG;
    atomicAdd(&out[g * 3 + 0], red[0][0] * inv);
    atomicAdd(&out[g * 3 + 1], red[1][0] * inv);
    atomicAdd(&out[g * 3 + 2], red[2][0] * inv);
  }
}

extern "C" void kernel_launch(void* const* d_in, const int* in_sizes, int n_in,
                              void* d_out, int out_size, void* d_ws, size_t ws_size,
                              hipStream_t stream) {
  const float* x  = (const float*)d_in[0];
  const int*   ei = (const int*)d_in[1];
  const float* W1 = (const float*)d_in[3];
  const float* b1 = (const float*)d_in[4];
  const float* W2 = (const float*)d_in[5];
  const float* b2 = (const float*)d_in[6];
  const int* row = ei;
  const int* col = ei + NE;
  float* out = (float*)d_out;

  // workspace layout (byte offsets)
  char* ws = (char*)d_ws;
  int*   cnt     = (int*)(ws + 0);                 // 512 KB
  float* dis     = (float*)(ws + (1u << 19));      // 512 KB
  int*   starts  = (int*)(ws + (2u << 19));        // 512 KB
  int*   cursor  = (int*)(ws + (3u << 19));        // 512 KB
  int*   partial = (int*)(ws + (4u << 19));        // 2 KB
  int*   pexcl   = (int*)(ws + (4u << 19) + 4096); // 2 KB
  int2*  edges   = (int2*)(ws + (5u << 19));       // 8 MB
  unsigned short* h1b = (unsigned short*)(ws + (5u << 19) + (1u << 23));  // 16 MB
  float* h2      = (float*)(ws + (5u << 19) + (1u << 23) + (1u << 24));   // 1.5 MB

  hipMemsetAsync(cnt, 0, NN * sizeof(int), stream);
  k_count<<<NE / 256, 256, 0, stream>>>(col, cnt);
  k_scan1<<<SCAN_B, 256, 0, stream>>>(cnt, partial);
  k_scan2<<<1, 512, 0, stream>>>(partial, pexcl);
  k_scan3<<<SCAN_B, 256, 0, stream>>>(cnt, pexcl, starts, cursor, dis);
  k_fill<<<NE / 256, 256, 0, stream>>>(row, col, dis, cursor, edges);
  k_gemm1<<<NN / 64, 256, 0, stream>>>(x, W1, h1b);
  k_agg1f<<<NN / 4, 256, 0, stream>>>(h1b, starts, cnt, edges, b1, W2, h2);
  k_initout<<<1, 96, 0, stream>>>(b2, out);
  k_agg2pool<<<NN / 256, 256, 0, stream>>>(h2, starts, cnt, edges, out);
}